// Round 19
// baseline (179.077 us; speedup 1.0000x reference)
//
#include <hip/hip_runtime.h>
#include <hip/hip_bf16.h>
#include <math.h>

// Problem constants
#define BS 32
#define SEQ 50
#define ML 16
#define NN 15
#define NTREE (BS*SEQ*ML)     // 25600
#define NROW (BS*SEQ)         // 1600
#define VOCAB 50000
#define EMB 128
#define ENC 128
#define GH 32
#define NC 100
#define LH 128
#define LIN_D 167             // 101 + 64 + 2

typedef float f32x4 __attribute__((ext_vector_type(4)));
typedef short s16x8 __attribute__((ext_vector_type(8)));
typedef unsigned int u32;
typedef u32 u32x4v __attribute__((ext_vector_type(4)));

#define LOG2E 1.4426950408889634f
__device__ __forceinline__ float fsig(float x) {
  return __builtin_amdgcn_rcpf(1.f + __builtin_amdgcn_exp2f(-LOG2E * x));
}
__device__ __forceinline__ float ftanh(float x) {
  return 2.f * __builtin_amdgcn_rcpf(
             1.f + __builtin_amdgcn_exp2f(-2.f * LOG2E * x)) - 1.f;
}
__device__ __forceinline__ u32 pkbf(float x, float y) {
  u32 a = __float_as_uint(x), b = __float_as_uint(y);
  a = (a + 0x7FFFu + ((a >> 16) & 1u)) >> 16;
  b = (b + 0x7FFFu + ((b >> 16) & 1u)) >> 16;
  return a | (b << 16);
}
__device__ __forceinline__ unsigned short f2bf(float x) {
  u32 a = __float_as_uint(x);
  return (unsigned short)((a + 0x7FFFu + ((a >> 16) & 1u)) >> 16);
}
#define MFMA __builtin_amdgcn_mfma_f32_16x16x32_bf16

// ---------------------------------------------------------------------------
// MERGED Ep GEMM + weight prep. Blocks < 782: Ep = emb @ Wc_w^T (bf16 out),
// Wc_w B-frags packed INLINE (L2-hot, bit-identical to the old Wcpk path).
// Blocks >= 782: pack Wallpk / Wxpk / Wpk / Wgpk / ball (old k_prep minus
// Wcpk). 974 blocks total.
// ---------------------------------------------------------------------------
__global__ __launch_bounds__(256) void k_ep_prep(
    const float* __restrict__ emb, const float* __restrict__ Wc_w,
    const float* __restrict__ WxF, const float* __restrict__ WxB,
    const float* __restrict__ bxF, const float* __restrict__ bxB,
    const float* __restrict__ lstm_Wx, const float* __restrict__ lstm_Wh,
    const float* __restrict__ gru_WhF, const float* __restrict__ gru_WhB,
    unsigned short* __restrict__ Epb, float* __restrict__ ball,
    u32* __restrict__ Wallpk, u32* __restrict__ Wxpk,
    u32* __restrict__ Wpk, u32* __restrict__ Wgpk) {
  int bid = blockIdx.x;
  if (bid >= 782) {
    int i = (bid - 782) * 256 + threadIdx.x;
    if (i < 96) ball[i] = bxF[i];
    else if (i < 192) ball[i] = bxB[i - 96];
    if (i < 12288) {  // Wallpk (N=192)
      int fg = i >> 8, l = (i >> 2) & 63, p = i & 3;
      int nt = fg >> 2, kt = fg & 3;
      int n = nt * 16 + (l & 15);
      int k = kt * 32 + (l >> 4) * 8 + 2 * p;
      float v0 = (n < 96) ? WxF[n * 128 + k]     : WxB[(n - 96) * 128 + k];
      float v1 = (n < 96) ? WxF[n * 128 + k + 1] : WxB[(n - 96) * 128 + k + 1];
      Wallpk[i] = pkbf(v0, v1);
    }
    if (i < 49152) {  // Wxpk (N=512, KT=6, K padded 167->192)
      int fg = i >> 8, l = (i >> 2) & 63, p = i & 3;
      int nt = fg / 6, kt = fg % 6;
      int n = nt * 16 + (l & 15);
      int k = kt * 32 + (l >> 4) * 8 + 2 * p;
      float v0 = (k < LIN_D)     ? lstm_Wx[n * LIN_D + k]     : 0.f;
      float v1 = (k + 1 < LIN_D) ? lstm_Wx[n * LIN_D + k + 1] : 0.f;
      Wxpk[i] = pkbf(v0, v1);
    }
    if (i < 32768) {  // Wpk: lstm wave-local gates. fg = w*16 + gt*4 + kt
      int fg = i >> 8, l = (i >> 2) & 63, p = i & 3;
      int w = fg >> 4, gt = (fg >> 2) & 3, kt = fg & 3;
      int n = 128 * gt + 16 * w + (l & 15);
      int k = 32 * kt + 8 * (l >> 4) + 2 * p;
      Wpk[i] = pkbf(lstm_Wh[n * 128 + k], lstm_Wh[n * 128 + k + 1]);
    }
    if (i < 3072) {   // Wgpk: GRU Wh (96x32), fg = dir*6 + nt
      int fg = i >> 8, l = (i >> 2) & 63, p = i & 3;
      int dir = fg / 6, nt = fg % 6;
      int n = nt * 16 + (l & 15);
      int k = (l >> 4) * 8 + 2 * p;
      const float* Wh = dir ? gru_WhB : gru_WhF;
      Wgpk[i] = pkbf(Wh[n * 32 + k], Wh[n * 32 + k + 1]);
    }
    return;
  }
  // ---- Ep GEMM part: M=VOCAB, N=128, out bf16, inline Wc B-pack ----
  int w = threadIdx.x >> 6, lane = threadIdx.x & 63;
  int R0 = bid * 64 + w * 16;
  int r = R0 + (lane & 15);
  int rm = (r < VOCAB) ? r : (VOCAB - 1);
  const float* Ar = emb + (size_t)rm * 128 + (lane >> 4) * 8;
  s16x8 a0, a1, a2, a3;
  {
#define LDA(AF, KT) { \
    float4 f0 = *(const float4*)(Ar + KT * 32); \
    float4 f1 = *(const float4*)(Ar + KT * 32 + 4); \
    u32x4v q = {pkbf(f0.x, f0.y), pkbf(f0.z, f0.w), \
                pkbf(f1.x, f1.y), pkbf(f1.z, f1.w)}; \
    AF = __builtin_bit_cast(s16x8, q); }
    LDA(a0, 0) LDA(a1, 1) LDA(a2, 2) LDA(a3, 3)
#undef LDA
  }
#define BLDB(BF, FG) { \
    int nn_ = ((FG) >> 2) * 16 + (lane & 15); \
    int kq_ = ((FG) & 3) * 32 + (lane >> 4) * 8; \
    const float* wr = Wc_w + nn_ * 128 + kq_; \
    float4 f0 = *(const float4*)wr; float4 f1 = *(const float4*)(wr + 4); \
    u32x4v q = {pkbf(f0.x, f0.y), pkbf(f0.z, f0.w), \
                pkbf(f1.x, f1.y), pkbf(f1.z, f1.w)}; \
    BF = __builtin_bit_cast(s16x8, q); }
  for (int c = 0; c < 128; c += 64) {
    f32x4 acc0 = {0,0,0,0}, acc1 = {0,0,0,0};
    f32x4 acc2 = {0,0,0,0}, acc3 = {0,0,0,0};
    int fbase = (c >> 4) * 4;
#define DONT(ACC, NT) { \
    s16x8 bf0, bf1, bf2, bf3; \
    BLDB(bf0, fbase + NT * 4 + 0) BLDB(bf1, fbase + NT * 4 + 1) \
    BLDB(bf2, fbase + NT * 4 + 2) BLDB(bf3, fbase + NT * 4 + 3) \
    ACC = MFMA(a0, bf0, ACC, 0, 0, 0); ACC = MFMA(a1, bf1, ACC, 0, 0, 0); \
    ACC = MFMA(a2, bf2, ACC, 0, 0, 0); ACC = MFMA(a3, bf3, ACC, 0, 0, 0); }
    DONT(acc0, 0) DONT(acc1, 1) DONT(acc2, 2) DONT(acc3, 3)
#undef DONT
    int colb = c + (lane & 15);
    int rowb = R0 + (lane >> 4) * 4;
#define STNT(ACC, NT) \
    _Pragma("unroll") \
    for (int j = 0; j < 4; j++) { \
      int row = rowb + j; \
      if (row < VOCAB) \
        Epb[(size_t)row * 128 + colb + NT * 16] = f2bf(ACC[j]); \
    }
    STNT(acc0, 0) STNT(acc1, 1) STNT(acc2, 2) STNT(acc3, 3)
#undef STNT
  }
#undef BLDB
}

// ---------------------------------------------------------------------------
// FUSED tree-gather + MFMA GEMM: xe_all = treeenc(ast, Epb, Wc_b) @ Wall^T
// + ball. 400 blocks x 64 rows.
// ---------------------------------------------------------------------------
__global__ __launch_bounds__(256) void k_tree_xe(
    const int* __restrict__ ast, const u32* __restrict__ Epb,
    const float* __restrict__ Wc_b, const u32* __restrict__ Bpk,
    const float* __restrict__ bias, float* __restrict__ Cout) {
  __shared__ int toks[64 * 15];
  int t = threadIdx.x, w = t >> 6, lane = t & 63;
  int R0 = blockIdx.x * 64;
  const int* ab = ast + (size_t)R0 * 15;
  #pragma unroll
  for (int i = t; i < 960; i += 256) toks[i] = ab[i];
  __syncthreads();
  int rl = w * 16 + (lane & 15);
  int q = lane >> 4;
  const u32x4v* Epg = (const u32x4v*)Epb;
  s16x8 afr0, afr1, afr2, afr3;
#define BUILD(AF, KT) { \
    u32x4v g[15]; \
    _Pragma("unroll") \
    for (int n = 0; n < 15; n++) \
      g[n] = Epg[(size_t)toks[rl * 15 + n] * 16 + KT * 4 + q]; \
    u32 outw[4]; \
    _Pragma("unroll") \
    for (int j = 0; j < 4; j++) { \
      float m2[2]; \
      _Pragma("unroll") \
      for (int hilo = 0; hilo < 2; hilo++) { \
        float e[15]; \
        _Pragma("unroll") \
        for (int n = 0; n < 15; n++) \
          e[n] = __uint_as_float(hilo ? (g[n][j] & 0xFFFF0000u) : (g[n][j] << 16)); \
        float b = Wc_b[KT * 32 + q * 8 + 2 * j + hilo]; \
        float s3 = e[3] + e[7] + e[8],  s4 = e[4] + e[9] + e[10]; \
        float s5 = e[5] + e[11] + e[12], s6 = e[6] + e[13] + e[14]; \
        float s1 = e[1] + s3 + s4, s2 = e[2] + s5 + s6; \
        float s0 = e[0] + s1 + s2; \
        float ml = fmaxf(fmaxf(fmaxf(e[7], e[8]), fmaxf(e[9], e[10])), \
                         fmaxf(fmaxf(e[11], e[12]), fmaxf(e[13], e[14]))) + b; \
        float mm = fmaxf(fmaxf(s3, s4), fmaxf(s5, s6)) + 3.f * b; \
        float mt = fmaxf(s1, s2) + 7.f * b; \
        m2[hilo] = fmaxf(fmaxf(ml, mm), fmaxf(mt, s0 + 15.f * b)); \
      } \
      outw[j] = pkbf(m2[0], m2[1]); \
    } \
    u32x4v qq = {outw[0], outw[1], outw[2], outw[3]}; \
    AF = __builtin_bit_cast(s16x8, qq); }
  BUILD(afr0, 0) BUILD(afr1, 1) BUILD(afr2, 2) BUILD(afr3, 3)
#undef BUILD
  const u32x4v* Bp = (const u32x4v*)Bpk;
  int R0w = R0 + w * 16;
  for (int c = 0; c < 192; c += 64) {
    f32x4 acc0, acc1, acc2, acc3;
    {
      float b0 = bias[c + (lane & 15)];
      float b1 = bias[c + 16 + (lane & 15)];
      float b2 = bias[c + 32 + (lane & 15)];
      float b3 = bias[c + 48 + (lane & 15)];
      acc0 = (f32x4){b0, b0, b0, b0}; acc1 = (f32x4){b1, b1, b1, b1};
      acc2 = (f32x4){b2, b2, b2, b2}; acc3 = (f32x4){b3, b3, b3, b3};
    }
    int fbase = (c >> 4) * 4;
#define DONT(ACC, NT) { \
    s16x8 bf0 = __builtin_bit_cast(s16x8, Bp[(size_t)(fbase + NT * 4 + 0) * 64 + lane]); \
    s16x8 bf1 = __builtin_bit_cast(s16x8, Bp[(size_t)(fbase + NT * 4 + 1) * 64 + lane]); \
    s16x8 bf2 = __builtin_bit_cast(s16x8, Bp[(size_t)(fbase + NT * 4 + 2) * 64 + lane]); \
    s16x8 bf3 = __builtin_bit_cast(s16x8, Bp[(size_t)(fbase + NT * 4 + 3) * 64 + lane]); \
    ACC = MFMA(afr0, bf0, ACC, 0, 0, 0); ACC = MFMA(afr1, bf1, ACC, 0, 0, 0); \
    ACC = MFMA(afr2, bf2, ACC, 0, 0, 0); ACC = MFMA(afr3, bf3, ACC, 0, 0, 0); }
    DONT(acc0, 0) DONT(acc1, 1) DONT(acc2, 2) DONT(acc3, 3)
#undef DONT
    int colb = c + (lane & 15);
    int rowb = R0w + (lane >> 4) * 4;
#define STNT(ACC, NT) \
    _Pragma("unroll") \
    for (int j = 0; j < 4; j++) \
      Cout[(size_t)(rowb + j) * 192 + colb + NT * 16] = ACC[j];
    STNT(acc0, 0) STNT(acc1, 1) STNT(acc2, 2) STNT(acc3, 3)
#undef STNT
  }
}

// ---------------------------------------------------------------------------
// Fused lin-gather + MFMA GEMM (K=192, KT=6): xeL.
// ---------------------------------------------------------------------------
__device__ __forceinline__ float lin_at(const float* __restrict__ ce,
    const float* __restrict__ co, const float* __restrict__ cu,
    int row, int k) {
  if (k < 101) return ce[row * 101 + k];
  if (k < 165) return co[row * 64 + (k - 101)];
  if (k < 167) return cu[row * 2 + (k - 165)];
  return 0.f;
}

__global__ __launch_bounds__(256) void gemm_lin(
    const float* __restrict__ c_embed, const float* __restrict__ code,
    const float* __restrict__ cur, const u32* __restrict__ Bpk,
    const float* __restrict__ bias, float* __restrict__ Cout) {
  int w = threadIdx.x >> 6, lane = threadIdx.x & 63;
  int R0 = blockIdx.x * 64 + w * 16;
  int r = R0 + (lane & 15);
  s16x8 a[6];
  #pragma unroll
  for (int kt = 0; kt < 6; kt++) {
    int k0 = kt * 32 + (lane >> 4) * 8;
    float f[8];
    #pragma unroll
    for (int j = 0; j < 8; j++) f[j] = lin_at(c_embed, code, cur, r, k0 + j);
    u32x4v q = {pkbf(f[0], f[1]), pkbf(f[2], f[3]),
                pkbf(f[4], f[5]), pkbf(f[6], f[7])};
    a[kt] = __builtin_bit_cast(s16x8, q);
  }
  const u32x4v* Bp = (const u32x4v*)Bpk;
  for (int c = 0; c < 512; c += 64) {
    f32x4 acc[4];
    #pragma unroll
    for (int nt = 0; nt < 4; nt++) {
      float bv = bias[c + nt * 16 + (lane & 15)];
      acc[nt] = (f32x4){bv, bv, bv, bv};
    }
    int fbase = (c >> 4) * 6;
    #pragma unroll
    for (int nt = 0; nt < 4; nt++) {
      #pragma unroll
      for (int kt = 0; kt < 6; kt++) {
        s16x8 bf = __builtin_bit_cast(s16x8,
            Bp[(size_t)(fbase + nt * 6 + kt) * 64 + lane]);
        acc[nt] = MFMA(a[kt], bf, acc[nt], 0, 0, 0);
      }
    }
    int colb = c + (lane & 15);
    int rowb = R0 + (lane >> 4) * 4;
    #pragma unroll
    for (int nt = 0; nt < 4; nt++)
      #pragma unroll
      for (int j = 0; j < 4; j++)
        Cout[(size_t)(rowb + j) * 512 + colb + nt * 16] = acc[nt][j];
  }
}

// ---------------------------------------------------------------------------
// GRU v2 (MFMA, one wave per (seq,dir), no barriers in the step loop).
// ---------------------------------------------------------------------------
__global__ __launch_bounds__(256) void k_gru(const float* __restrict__ xe_all,
    const u32* __restrict__ Wgpk, const float* __restrict__ bhF,
    const float* __restrict__ bhB, float* __restrict__ code) {
  __shared__ float xls[32 * 192];
  __shared__ short hls[4][32];
  int t = threadIdx.x, w = t >> 6, lane = t & 63;
  int sq0 = blockIdx.x * 2;
  const float* xb = xe_all + (size_t)sq0 * 16 * 192;
  #pragma unroll 4
  for (int i = t; i < 32 * 192; i += 256) xls[i] = xb[i];
  int sql = w >> 1, dir = w & 1;
  int seq = sq0 + sql;
  const s16x8* BG = (const s16x8*)Wgpk + (size_t)dir * 6 * 64 + lane;
  s16x8 G0 = BG[0], G1 = BG[64], G2 = BG[128];
  s16x8 G3 = BG[192], G4 = BG[256], G5 = BG[320];
  const float* bh = dir ? bhB : bhF;
  float bh0 = 0, bh1 = 0, bh2 = 0, bh3 = 0, bh4 = 0, bh5 = 0;
  if (lane < 16) {
    bh0 = bh[lane];      bh1 = bh[16 + lane]; bh2 = bh[32 + lane];
    bh3 = bh[48 + lane]; bh4 = bh[64 + lane]; bh5 = bh[80 + lane];
  }
  float h0 = 0.f, h1 = 0.f, mx0 = -1e30f, mx1 = -1e30f;
  hls[w][lane & 31] = 0;
  __syncthreads();
  const s16x8 zz = {0, 0, 0, 0, 0, 0, 0, 0};
  const bool arow = (lane & 15) == 0;
  const int aoff = (lane >> 4) * 8;
  for (int s = 0; s < 16; s++) {
    int tt = dir ? (15 - s) : s;
    const float* xr = xls + (sql * 16 + tt) * 192 + dir * 96;
    s16x8 a = arow ? *(const s16x8*)&hls[w][aoff] : zz;
    f32x4 ac0 = {0,0,0,0}, ac1 = {0,0,0,0}, ac2 = {0,0,0,0};
    f32x4 ac3 = {0,0,0,0}, ac4 = {0,0,0,0}, ac5 = {0,0,0,0};
    float xn0 = 0.f, xn1 = 0.f;
    if (lane < 16) {
      ac0[0] = xr[lane] + bh0;      ac1[0] = xr[16 + lane] + bh1;
      ac2[0] = xr[32 + lane] + bh2; ac3[0] = xr[48 + lane] + bh3;
      ac4[0] = bh4;                 ac5[0] = bh5;
      xn0 = xr[64 + lane];          xn1 = xr[80 + lane];
    }
    ac0 = MFMA(a, G0, ac0, 0, 0, 0); ac1 = MFMA(a, G1, ac1, 0, 0, 0);
    ac2 = MFMA(a, G2, ac2, 0, 0, 0); ac3 = MFMA(a, G3, ac3, 0, 0, 0);
    ac4 = MFMA(a, G4, ac4, 0, 0, 0); ac5 = MFMA(a, G5, ac5, 0, 0, 0);
    if (lane < 16) {
      float r0 = fsig(ac0[0]), r1 = fsig(ac1[0]);
      float z0 = fsig(ac2[0]), z1 = fsig(ac3[0]);
      float n0 = ftanh(xn0 + r0 * ac4[0]);
      float n1 = ftanh(xn1 + r1 * ac5[0]);
      h0 = (1.f - z0) * n0 + z0 * h0;
      h1 = (1.f - z1) * n1 + z1 * h1;
      mx0 = fmaxf(mx0, h0); mx1 = fmaxf(mx1, h1);
      hls[w][lane]      = (short)f2bf(h0);
      hls[w][16 + lane] = (short)f2bf(h1);
    }
  }
  if (lane < 16) {
    code[(size_t)seq * 64 + dir * 32 + lane]      = mx0;
    code[(size_t)seq * 64 + dir * 32 + 16 + lane] = mx1;
  }
}

// ---------------------------------------------------------------------------
// FUSED LSTM + prediction head: lstm (MFMA, wave-local gates) keeps the h
// history in LDS; the pred head runs in the same block (wave-per-row,
// shfl butterfly reduces) -> no lout materialization, no 1600-block launch.
// One-hot fast path + generic fallback (identical numerics to old k_pred).
// ---------------------------------------------------------------------------
__global__ __launch_bounds__(512) void k_lstm_pred(
    const float* __restrict__ xeL, const u32* __restrict__ Wpk,
    const float* __restrict__ bh, const float* __restrict__ pred_w,
    const float* __restrict__ pred_b, const float* __restrict__ tc,
    const float* __restrict__ result, float* __restrict__ out,
    float* __restrict__ fpbuf, float* __restrict__ mbuf) {
  __shared__ float xl[SEQ * 512];
  __shared__ float hh[SEQ * 128];
  __shared__ s16x8 hl8[16];
  __shared__ float tcl[8][104];
  short* hls = (short*)hl8;
  int b = blockIdx.x, t = threadIdx.x;
  int w = t >> 6, lane = t & 63;
  const float* xrow = xeL + (size_t)b * SEQ * 512;
  #pragma unroll 5
  for (int i = t; i < SEQ * 512; i += 512) xl[i] = xrow[i];
  const s16x8* WB = (const s16x8*)Wpk + (size_t)w * 16 * 64 + lane;
  s16x8 B00 = WB[0*64],  B01 = WB[1*64],  B02 = WB[2*64],  B03 = WB[3*64];
  s16x8 B10 = WB[4*64],  B11 = WB[5*64],  B12 = WB[6*64],  B13 = WB[7*64];
  s16x8 B20 = WB[8*64],  B21 = WB[9*64],  B22 = WB[10*64], B23 = WB[11*64];
  s16x8 B30 = WB[12*64], B31 = WB[13*64], B32 = WB[14*64], B33 = WB[15*64];

  int u16 = 16 * w + lane;
  float bh0 = 0, bh1 = 0, bh2 = 0, bh3 = 0;
  if (lane < 16) {
    bh0 = bh[u16]; bh1 = bh[128 + u16]; bh2 = bh[256 + u16]; bh3 = bh[384 + u16];
  }
  float c = 0.f;
  if (t < 128) hls[t] = 0;
  __syncthreads();
  const s16x8 zz = {0, 0, 0, 0, 0, 0, 0, 0};
  const bool arow = (lane & 15) == 0;
  const int asel = lane >> 4;
  for (int step = 0; step < SEQ; step++) {
    s16x8 a0 = arow ? hl8[asel]      : zz;
    s16x8 a1 = arow ? hl8[4 + asel]  : zz;
    s16x8 a2 = arow ? hl8[8 + asel]  : zz;
    s16x8 a3 = arow ? hl8[12 + asel] : zz;
    f32x4 acc0 = {0, 0, 0, 0}, acc1 = {0, 0, 0, 0};
    f32x4 acc2 = {0, 0, 0, 0}, acc3 = {0, 0, 0, 0};
    if (lane < 16) {
      const float* xs = xl + step * 512;
      acc0[0] = xs[u16]       + bh0;   // i
      acc1[0] = xs[128 + u16] + bh1;   // f
      acc2[0] = xs[256 + u16] + bh2;   // g
      acc3[0] = xs[384 + u16] + bh3;   // o
    }
    acc0 = MFMA(a0, B00, acc0, 0, 0, 0); acc0 = MFMA(a1, B01, acc0, 0, 0, 0);
    acc0 = MFMA(a2, B02, acc0, 0, 0, 0); acc0 = MFMA(a3, B03, acc0, 0, 0, 0);
    acc1 = MFMA(a0, B10, acc1, 0, 0, 0); acc1 = MFMA(a1, B11, acc1, 0, 0, 0);
    acc1 = MFMA(a2, B12, acc1, 0, 0, 0); acc1 = MFMA(a3, B13, acc1, 0, 0, 0);
    acc2 = MFMA(a0, B20, acc2, 0, 0, 0); acc2 = MFMA(a1, B21, acc2, 0, 0, 0);
    acc2 = MFMA(a2, B22, acc2, 0, 0, 0); acc2 = MFMA(a3, B23, acc2, 0, 0, 0);
    acc3 = MFMA(a0, B30, acc3, 0, 0, 0); acc3 = MFMA(a1, B31, acc3, 0, 0, 0);
    acc3 = MFMA(a2, B32, acc3, 0, 0, 0); acc3 = MFMA(a3, B33, acc3, 0, 0, 0);
    if (lane < 16) {
      float iv = fsig(acc0[0]);
      float fv = fsig(acc1[0]);
      float gv = ftanh(acc2[0]);
      float ov = fsig(acc3[0]);
      c = fv * c + iv * gv;
      float h = ov * ftanh(c);
      hh[step * 128 + u16] = h;
      hls[u16] = (short)f2bf(h);
    }
    __syncthreads();
  }
  // ---- fused prediction head: wave w handles rows w, w+8, ... ----
  for (int tr = w; tr < SEQ; tr += 8) {
    int row = b * SEQ + tr;
    const float* tcr = tc + (size_t)row * 101;
    float tc0 = tcr[lane];                          // k = lane (0..63)
    float tc1 = (lane < 37) ? tcr[64 + lane] : 0.f; // k = 64..100
    tcl[w][lane] = tc0;
    if (lane < 37) tcl[w][64 + lane] = tc1;
    float nz = ((tc0 != 0.f) ? 1.f : 0.f) + ((tc1 != 0.f) ? 1.f : 0.f);
    float ixs = ((tc0 != 0.f) ? (float)lane : 0.f) +
                ((tc1 != 0.f) ? (float)(64 + lane) : 0.f);
    float vs = tc0 + tc1;
    #pragma unroll
    for (int mskk = 32; mskk; mskk >>= 1) {
      nz  += __shfl_xor(nz, mskk);
      ixs += __shfl_xor(ixs, mskk);
      vs  += __shfl_xor(vs, mskk);
    }
    float fp, mval;
    if (nz == 1.f && vs == 1.f) {
      int cls = (int)ixs;
      const float* pw = pred_w + cls * 128;
      float p = hh[tr * 128 + lane] * pw[lane]
              + hh[tr * 128 + 64 + lane] * pw[64 + lane];
      #pragma unroll
      for (int mskk = 32; mskk; mskk >>= 1) p += __shfl_xor(p, mskk);
      fp = p + pred_b[cls];
      mval = 1.f;
    } else {
      float v = 0.f;
      #pragma unroll
      for (int kk = 0; kk < 2; kk++) {
        int k = lane + kk * 64;
        float acc = 0.f;
        for (int cc = 0; cc < 101; cc++) acc += tcl[w][cc] * pred_w[cc * 128 + k];
        v += acc * hh[tr * 128 + k];
      }
      float pb = tc0 * pred_b[lane];
      if (lane < 37) pb += tc1 * pred_b[64 + lane];
      float tot = v + pb;
      #pragma unroll
      for (int mskk = 32; mskk; mskk >>= 1) tot += __shfl_xor(tot, mskk);
      mval = (vs > 0.f) ? 1.f : 0.f;
      fp = tot / fmaxf(vs, 1.f);
    }
    if (lane == 0) {
      fpbuf[row] = fp; mbuf[row] = mval;
      out[1 + row] = mval / (1.f + expf(-fp));
      out[1 + NROW + row] = result[row] * mval;
    }
  }
}

// ---------------------------------------------------------------------------
// Loss reduction (single block, deterministic tree reduce)
// ---------------------------------------------------------------------------
__global__ __launch_bounds__(256) void k_loss(const float* __restrict__ fpbuf,
    const float* __restrict__ mbuf, const float* __restrict__ result,
    float* __restrict__ out) {
  __shared__ float sb[256], sm[256];
  int k = threadIdx.x;
  float ab = 0.f, am = 0.f;
  for (int r = k; r < NROW; r += 256) {
    float fp = fpbuf[r], m = mbuf[r], res = result[r];
    float bce = fmaxf(fp, 0.f) - fp * res + log1pf(expf(-fabsf(fp)));
    ab += bce * m; am += m;
  }
  sb[k] = ab; sm[k] = am;
  __syncthreads();
  for (int st = 128; st > 0; st >>= 1) {
    if (k < st) { sb[k] += sb[k + st]; sm[k] += sm[k + st]; }
    __syncthreads();
  }
  if (k == 0) out[0] = sb[0] / fmaxf(sm[0], 1.f);
}

// ---------------------------------------------------------------------------
extern "C" void kernel_launch(void* const* d_in, const int* in_sizes, int n_in,
                              void* d_out, int out_size, void* d_ws, size_t ws_size,
                              hipStream_t stream) {
  (void)in_sizes; (void)n_in; (void)out_size; (void)ws_size;
  const int*   ast      = (const int*)  d_in[2];
  const float* target_c = (const float*)d_in[3];
  const float* c_embed  = (const float*)d_in[4];
  const float* cur_res  = (const float*)d_in[5];
  const float* result   = (const float*)d_in[6];
  const float* emb      = (const float*)d_in[7];
  const float* Wc_w     = (const float*)d_in[8];
  const float* Wc_b     = (const float*)d_in[9];
  const float* gru_WxF  = (const float*)d_in[10];
  const float* gru_WhF  = (const float*)d_in[11];
  const float* gru_bxF  = (const float*)d_in[12];
  const float* gru_bhF  = (const float*)d_in[13];
  const float* gru_WxB  = (const float*)d_in[14];
  const float* gru_WhB  = (const float*)d_in[15];
  const float* gru_bxB  = (const float*)d_in[16];
  const float* gru_bhB  = (const float*)d_in[17];
  const float* lstm_Wx  = (const float*)d_in[18];
  const float* lstm_Wh  = (const float*)d_in[19];
  const float* lstm_bx  = (const float*)d_in[20];
  const float* lstm_bh  = (const float*)d_in[21];
  const float* pred_w   = (const float*)d_in[22];
  const float* pred_b   = (const float*)d_in[23];
  float* out = (float*)d_out;

  float* W = (float*)d_ws;
  u32*   Epb    = (u32*)W;                       // 3,200,000 (50000x128 bf16)
  float* xe_all = W + 3200000;                   // 4,915,200
  float* code   = W + 8115200;                   // 102,400
  float* xeL    = W + 8217600;                   // 819,200
  float* fpbuf  = W + 9036800;                   // 1,600
  float* mbuf   = W + 9038400;                   // 1,600
  u32*   Wallpk = (u32*)(W + 9040000);           // 12,288
  u32*   Wxpk   = (u32*)(W + 9052288);           // 49,152
  u32*   Wpk    = (u32*)(W + 9101440);           // 32,768
  float* ball   = W + 9134208;                   // 192
  u32*   Wgpk   = (u32*)(W + 9134400);           // 3,072

  // 1. MERGED: Ep = emb @ Wc_w^T (inline B-pack, bf16 out) + weight prep
  k_ep_prep<<<974, 256, 0, stream>>>(emb, Wc_w, gru_WxF, gru_WxB, gru_bxF,
                                     gru_bxB, lstm_Wx, lstm_Wh, gru_WhF,
                                     gru_WhB, (unsigned short*)Epb, ball,
                                     Wallpk, Wxpk, Wpk, Wgpk);
  // 2. FUSED tree gather/sum/max + xe_all GEMM (MFMA, fp32 out, N=192)
  k_tree_xe<<<400, 256, 0, stream>>>(ast, Epb, Wc_b, Wallpk, ball, xe_all);
  // 3. GRU recurrence + time max -> code (MFMA, wave per (seq,dir))
  k_gru<<<NROW / 2, 256, 0, stream>>>(xe_all, Wgpk, gru_bhF, gru_bhB, code);
  // 4. xeL = [c_embed|code|cur|0] @ lstm_Wx^T + lstm_bx (fused lin, K=192 MFMA)
  gemm_lin<<<25, 256, 0, stream>>>(c_embed, code, cur_res, Wxpk, lstm_bx, xeL);
  // 5. FUSED LSTM recurrence + prediction head (no lout materialization)
  k_lstm_pred<<<BS, 512, 0, stream>>>(xeL, Wpk, lstm_bh, pred_w, pred_b,
                                      target_c, result, out, fpbuf, mbuf);
  // 6. loss -> out[0]
  k_loss<<<1, 256, 0, stream>>>(fpbuf, mbuf, result, out);
}

// Round 20
// 153.453 us; speedup vs baseline: 1.1670x; 1.1670x over previous
//
#include <hip/hip_runtime.h>
#include <hip/hip_bf16.h>
#include <math.h>

// Problem constants
#define BS 32
#define SEQ 50
#define ML 16
#define NN 15
#define NTREE (BS*SEQ*ML)     // 25600
#define NROW (BS*SEQ)         // 1600
#define VOCAB 50000
#define EMB 128
#define ENC 128
#define GH 32
#define NC 100
#define LH 128
#define LIN_D 167             // 101 + 64 + 2

typedef float f32x4 __attribute__((ext_vector_type(4)));
typedef short s16x8 __attribute__((ext_vector_type(8)));
typedef unsigned int u32;
typedef u32 u32x4v __attribute__((ext_vector_type(4)));

#define LOG2E 1.4426950408889634f
__device__ __forceinline__ float fsig(float x) {
  return __builtin_amdgcn_rcpf(1.f + __builtin_amdgcn_exp2f(-LOG2E * x));
}
__device__ __forceinline__ float ftanh(float x) {
  return 2.f * __builtin_amdgcn_rcpf(
             1.f + __builtin_amdgcn_exp2f(-2.f * LOG2E * x)) - 1.f;
}
__device__ __forceinline__ u32 pkbf(float x, float y) {
  u32 a = __float_as_uint(x), b = __float_as_uint(y);
  a = (a + 0x7FFFu + ((a >> 16) & 1u)) >> 16;
  b = (b + 0x7FFFu + ((b >> 16) & 1u)) >> 16;
  return a | (b << 16);
}
__device__ __forceinline__ unsigned short f2bf(float x) {
  u32 a = __float_as_uint(x);
  return (unsigned short)((a + 0x7FFFu + ((a >> 16) & 1u)) >> 16);
}
#define MFMA __builtin_amdgcn_mfma_f32_16x16x32_bf16

// ---------------------------------------------------------------------------
// MERGED Ep GEMM + weight prep. Blocks < 782: Ep = emb @ Wc_w^T (bf16 out),
// Wc_w B-frags packed INLINE. Blocks >= 782: pack Wallpk/Wxpk/Wpk/Wgpk/ball.
// ---------------------------------------------------------------------------
__global__ __launch_bounds__(256) void k_ep_prep(
    const float* __restrict__ emb, const float* __restrict__ Wc_w,
    const float* __restrict__ WxF, const float* __restrict__ WxB,
    const float* __restrict__ bxF, const float* __restrict__ bxB,
    const float* __restrict__ lstm_Wx, const float* __restrict__ lstm_Wh,
    const float* __restrict__ gru_WhF, const float* __restrict__ gru_WhB,
    unsigned short* __restrict__ Epb, float* __restrict__ ball,
    u32* __restrict__ Wallpk, u32* __restrict__ Wxpk,
    u32* __restrict__ Wpk, u32* __restrict__ Wgpk) {
  int bid = blockIdx.x;
  if (bid >= 782) {
    int i = (bid - 782) * 256 + threadIdx.x;
    if (i < 96) ball[i] = bxF[i];
    else if (i < 192) ball[i] = bxB[i - 96];
    if (i < 12288) {  // Wallpk (N=192)
      int fg = i >> 8, l = (i >> 2) & 63, p = i & 3;
      int nt = fg >> 2, kt = fg & 3;
      int n = nt * 16 + (l & 15);
      int k = kt * 32 + (l >> 4) * 8 + 2 * p;
      float v0 = (n < 96) ? WxF[n * 128 + k]     : WxB[(n - 96) * 128 + k];
      float v1 = (n < 96) ? WxF[n * 128 + k + 1] : WxB[(n - 96) * 128 + k + 1];
      Wallpk[i] = pkbf(v0, v1);
    }
    if (i < 49152) {  // Wxpk (N=512, KT=6, K padded 167->192)
      int fg = i >> 8, l = (i >> 2) & 63, p = i & 3;
      int nt = fg / 6, kt = fg % 6;
      int n = nt * 16 + (l & 15);
      int k = kt * 32 + (l >> 4) * 8 + 2 * p;
      float v0 = (k < LIN_D)     ? lstm_Wx[n * LIN_D + k]     : 0.f;
      float v1 = (k + 1 < LIN_D) ? lstm_Wx[n * LIN_D + k + 1] : 0.f;
      Wxpk[i] = pkbf(v0, v1);
    }
    if (i < 32768) {  // Wpk: lstm wave-local gates. fg = w*16 + gt*4 + kt
      int fg = i >> 8, l = (i >> 2) & 63, p = i & 3;
      int w = fg >> 4, gt = (fg >> 2) & 3, kt = fg & 3;
      int n = 128 * gt + 16 * w + (l & 15);
      int k = 32 * kt + 8 * (l >> 4) + 2 * p;
      Wpk[i] = pkbf(lstm_Wh[n * 128 + k], lstm_Wh[n * 128 + k + 1]);
    }
    if (i < 3072) {   // Wgpk: GRU Wh (96x32), fg = dir*6 + nt
      int fg = i >> 8, l = (i >> 2) & 63, p = i & 3;
      int dir = fg / 6, nt = fg % 6;
      int n = nt * 16 + (l & 15);
      int k = (l >> 4) * 8 + 2 * p;
      const float* Wh = dir ? gru_WhB : gru_WhF;
      Wgpk[i] = pkbf(Wh[n * 32 + k], Wh[n * 32 + k + 1]);
    }
    return;
  }
  // ---- Ep GEMM part ----
  int w = threadIdx.x >> 6, lane = threadIdx.x & 63;
  int R0 = bid * 64 + w * 16;
  int r = R0 + (lane & 15);
  int rm = (r < VOCAB) ? r : (VOCAB - 1);
  const float* Ar = emb + (size_t)rm * 128 + (lane >> 4) * 8;
  s16x8 a0, a1, a2, a3;
  {
#define LDA(AF, KT) { \
    float4 f0 = *(const float4*)(Ar + KT * 32); \
    float4 f1 = *(const float4*)(Ar + KT * 32 + 4); \
    u32x4v q = {pkbf(f0.x, f0.y), pkbf(f0.z, f0.w), \
                pkbf(f1.x, f1.y), pkbf(f1.z, f1.w)}; \
    AF = __builtin_bit_cast(s16x8, q); }
    LDA(a0, 0) LDA(a1, 1) LDA(a2, 2) LDA(a3, 3)
#undef LDA
  }
#define BLDB(BF, FG) { \
    int nn_ = ((FG) >> 2) * 16 + (lane & 15); \
    int kq_ = ((FG) & 3) * 32 + (lane >> 4) * 8; \
    const float* wr = Wc_w + nn_ * 128 + kq_; \
    float4 f0 = *(const float4*)wr; float4 f1 = *(const float4*)(wr + 4); \
    u32x4v q = {pkbf(f0.x, f0.y), pkbf(f0.z, f0.w), \
                pkbf(f1.x, f1.y), pkbf(f1.z, f1.w)}; \
    BF = __builtin_bit_cast(s16x8, q); }
  for (int c = 0; c < 128; c += 64) {
    f32x4 acc0 = {0,0,0,0}, acc1 = {0,0,0,0};
    f32x4 acc2 = {0,0,0,0}, acc3 = {0,0,0,0};
    int fbase = (c >> 4) * 4;
#define DONT(ACC, NT) { \
    s16x8 bf0, bf1, bf2, bf3; \
    BLDB(bf0, fbase + NT * 4 + 0) BLDB(bf1, fbase + NT * 4 + 1) \
    BLDB(bf2, fbase + NT * 4 + 2) BLDB(bf3, fbase + NT * 4 + 3) \
    ACC = MFMA(a0, bf0, ACC, 0, 0, 0); ACC = MFMA(a1, bf1, ACC, 0, 0, 0); \
    ACC = MFMA(a2, bf2, ACC, 0, 0, 0); ACC = MFMA(a3, bf3, ACC, 0, 0, 0); }
    DONT(acc0, 0) DONT(acc1, 1) DONT(acc2, 2) DONT(acc3, 3)
#undef DONT
    int colb = c + (lane & 15);
    int rowb = R0 + (lane >> 4) * 4;
#define STNT(ACC, NT) \
    _Pragma("unroll") \
    for (int j = 0; j < 4; j++) { \
      int row = rowb + j; \
      if (row < VOCAB) \
        Epb[(size_t)row * 128 + colb + NT * 16] = f2bf(ACC[j]); \
    }
    STNT(acc0, 0) STNT(acc1, 1) STNT(acc2, 2) STNT(acc3, 3)
#undef STNT
  }
#undef BLDB
}

// ---------------------------------------------------------------------------
// FUSED tree-gather + MFMA GEMM: xe_all = treeenc(ast, Epb, Wc_b) @ Wall^T
// + ball. 400 blocks x 64 rows.
// ---------------------------------------------------------------------------
__global__ __launch_bounds__(256) void k_tree_xe(
    const int* __restrict__ ast, const u32* __restrict__ Epb,
    const float* __restrict__ Wc_b, const u32* __restrict__ Bpk,
    const float* __restrict__ bias, float* __restrict__ Cout) {
  __shared__ int toks[64 * 15];
  int t = threadIdx.x, w = t >> 6, lane = t & 63;
  int R0 = blockIdx.x * 64;
  const int* ab = ast + (size_t)R0 * 15;
  #pragma unroll
  for (int i = t; i < 960; i += 256) toks[i] = ab[i];
  __syncthreads();
  int rl = w * 16 + (lane & 15);
  int q = lane >> 4;
  const u32x4v* Epg = (const u32x4v*)Epb;
  s16x8 afr0, afr1, afr2, afr3;
#define BUILD(AF, KT) { \
    u32x4v g[15]; \
    _Pragma("unroll") \
    for (int n = 0; n < 15; n++) \
      g[n] = Epg[(size_t)toks[rl * 15 + n] * 16 + KT * 4 + q]; \
    u32 outw[4]; \
    _Pragma("unroll") \
    for (int j = 0; j < 4; j++) { \
      float m2[2]; \
      _Pragma("unroll") \
      for (int hilo = 0; hilo < 2; hilo++) { \
        float e[15]; \
        _Pragma("unroll") \
        for (int n = 0; n < 15; n++) \
          e[n] = __uint_as_float(hilo ? (g[n][j] & 0xFFFF0000u) : (g[n][j] << 16)); \
        float b = Wc_b[KT * 32 + q * 8 + 2 * j + hilo]; \
        float s3 = e[3] + e[7] + e[8],  s4 = e[4] + e[9] + e[10]; \
        float s5 = e[5] + e[11] + e[12], s6 = e[6] + e[13] + e[14]; \
        float s1 = e[1] + s3 + s4, s2 = e[2] + s5 + s6; \
        float s0 = e[0] + s1 + s2; \
        float ml = fmaxf(fmaxf(fmaxf(e[7], e[8]), fmaxf(e[9], e[10])), \
                         fmaxf(fmaxf(e[11], e[12]), fmaxf(e[13], e[14]))) + b; \
        float mm = fmaxf(fmaxf(s3, s4), fmaxf(s5, s6)) + 3.f * b; \
        float mt = fmaxf(s1, s2) + 7.f * b; \
        m2[hilo] = fmaxf(fmaxf(ml, mm), fmaxf(mt, s0 + 15.f * b)); \
      } \
      outw[j] = pkbf(m2[0], m2[1]); \
    } \
    u32x4v qq = {outw[0], outw[1], outw[2], outw[3]}; \
    AF = __builtin_bit_cast(s16x8, qq); }
  BUILD(afr0, 0) BUILD(afr1, 1) BUILD(afr2, 2) BUILD(afr3, 3)
#undef BUILD
  const u32x4v* Bp = (const u32x4v*)Bpk;
  int R0w = R0 + w * 16;
  for (int c = 0; c < 192; c += 64) {
    f32x4 acc0, acc1, acc2, acc3;
    {
      float b0 = bias[c + (lane & 15)];
      float b1 = bias[c + 16 + (lane & 15)];
      float b2 = bias[c + 32 + (lane & 15)];
      float b3 = bias[c + 48 + (lane & 15)];
      acc0 = (f32x4){b0, b0, b0, b0}; acc1 = (f32x4){b1, b1, b1, b1};
      acc2 = (f32x4){b2, b2, b2, b2}; acc3 = (f32x4){b3, b3, b3, b3};
    }
    int fbase = (c >> 4) * 4;
#define DONT(ACC, NT) { \
    s16x8 bf0 = __builtin_bit_cast(s16x8, Bp[(size_t)(fbase + NT * 4 + 0) * 64 + lane]); \
    s16x8 bf1 = __builtin_bit_cast(s16x8, Bp[(size_t)(fbase + NT * 4 + 1) * 64 + lane]); \
    s16x8 bf2 = __builtin_bit_cast(s16x8, Bp[(size_t)(fbase + NT * 4 + 2) * 64 + lane]); \
    s16x8 bf3 = __builtin_bit_cast(s16x8, Bp[(size_t)(fbase + NT * 4 + 3) * 64 + lane]); \
    ACC = MFMA(afr0, bf0, ACC, 0, 0, 0); ACC = MFMA(afr1, bf1, ACC, 0, 0, 0); \
    ACC = MFMA(afr2, bf2, ACC, 0, 0, 0); ACC = MFMA(afr3, bf3, ACC, 0, 0, 0); }
    DONT(acc0, 0) DONT(acc1, 1) DONT(acc2, 2) DONT(acc3, 3)
#undef DONT
    int colb = c + (lane & 15);
    int rowb = R0w + (lane >> 4) * 4;
#define STNT(ACC, NT) \
    _Pragma("unroll") \
    for (int j = 0; j < 4; j++) \
      Cout[(size_t)(rowb + j) * 192 + colb + NT * 16] = ACC[j];
    STNT(acc0, 0) STNT(acc1, 1) STNT(acc2, 2) STNT(acc3, 3)
#undef STNT
  }
}

// ---------------------------------------------------------------------------
// Fused lin-gather + MFMA GEMM (K=192, KT=6): xeL.
// ---------------------------------------------------------------------------
__device__ __forceinline__ float lin_at(const float* __restrict__ ce,
    const float* __restrict__ co, const float* __restrict__ cu,
    int row, int k) {
  if (k < 101) return ce[row * 101 + k];
  if (k < 165) return co[row * 64 + (k - 101)];
  if (k < 167) return cu[row * 2 + (k - 165)];
  return 0.f;
}

__global__ __launch_bounds__(256) void gemm_lin(
    const float* __restrict__ c_embed, const float* __restrict__ code,
    const float* __restrict__ cur, const u32* __restrict__ Bpk,
    const float* __restrict__ bias, float* __restrict__ Cout) {
  int w = threadIdx.x >> 6, lane = threadIdx.x & 63;
  int R0 = blockIdx.x * 64 + w * 16;
  int r = R0 + (lane & 15);
  s16x8 a[6];
  #pragma unroll
  for (int kt = 0; kt < 6; kt++) {
    int k0 = kt * 32 + (lane >> 4) * 8;
    float f[8];
    #pragma unroll
    for (int j = 0; j < 8; j++) f[j] = lin_at(c_embed, code, cur, r, k0 + j);
    u32x4v q = {pkbf(f[0], f[1]), pkbf(f[2], f[3]),
                pkbf(f[4], f[5]), pkbf(f[6], f[7])};
    a[kt] = __builtin_bit_cast(s16x8, q);
  }
  const u32x4v* Bp = (const u32x4v*)Bpk;
  for (int c = 0; c < 512; c += 64) {
    f32x4 acc[4];
    #pragma unroll
    for (int nt = 0; nt < 4; nt++) {
      float bv = bias[c + nt * 16 + (lane & 15)];
      acc[nt] = (f32x4){bv, bv, bv, bv};
    }
    int fbase = (c >> 4) * 6;
    #pragma unroll
    for (int nt = 0; nt < 4; nt++) {
      #pragma unroll
      for (int kt = 0; kt < 6; kt++) {
        s16x8 bf = __builtin_bit_cast(s16x8,
            Bp[(size_t)(fbase + nt * 6 + kt) * 64 + lane]);
        acc[nt] = MFMA(a[kt], bf, acc[nt], 0, 0, 0);
      }
    }
    int colb = c + (lane & 15);
    int rowb = R0 + (lane >> 4) * 4;
    #pragma unroll
    for (int nt = 0; nt < 4; nt++)
      #pragma unroll
      for (int j = 0; j < 4; j++)
        Cout[(size_t)(rowb + j) * 512 + colb + nt * 16] = acc[nt][j];
  }
}

// ---------------------------------------------------------------------------
// GRU v2 (MFMA, one wave per (seq,dir), no barriers in the step loop).
// ---------------------------------------------------------------------------
__global__ __launch_bounds__(256) void k_gru(const float* __restrict__ xe_all,
    const u32* __restrict__ Wgpk, const float* __restrict__ bhF,
    const float* __restrict__ bhB, float* __restrict__ code) {
  __shared__ float xls[32 * 192];
  __shared__ short hls[4][32];
  int t = threadIdx.x, w = t >> 6, lane = t & 63;
  int sq0 = blockIdx.x * 2;
  const float* xb = xe_all + (size_t)sq0 * 16 * 192;
  #pragma unroll 4
  for (int i = t; i < 32 * 192; i += 256) xls[i] = xb[i];
  int sql = w >> 1, dir = w & 1;
  int seq = sq0 + sql;
  const s16x8* BG = (const s16x8*)Wgpk + (size_t)dir * 6 * 64 + lane;
  s16x8 G0 = BG[0], G1 = BG[64], G2 = BG[128];
  s16x8 G3 = BG[192], G4 = BG[256], G5 = BG[320];
  const float* bh = dir ? bhB : bhF;
  float bh0 = 0, bh1 = 0, bh2 = 0, bh3 = 0, bh4 = 0, bh5 = 0;
  if (lane < 16) {
    bh0 = bh[lane];      bh1 = bh[16 + lane]; bh2 = bh[32 + lane];
    bh3 = bh[48 + lane]; bh4 = bh[64 + lane]; bh5 = bh[80 + lane];
  }
  float h0 = 0.f, h1 = 0.f, mx0 = -1e30f, mx1 = -1e30f;
  hls[w][lane & 31] = 0;
  __syncthreads();
  const s16x8 zz = {0, 0, 0, 0, 0, 0, 0, 0};
  const bool arow = (lane & 15) == 0;
  const int aoff = (lane >> 4) * 8;
  for (int s = 0; s < 16; s++) {
    int tt = dir ? (15 - s) : s;
    const float* xr = xls + (sql * 16 + tt) * 192 + dir * 96;
    s16x8 a = arow ? *(const s16x8*)&hls[w][aoff] : zz;
    f32x4 ac0 = {0,0,0,0}, ac1 = {0,0,0,0}, ac2 = {0,0,0,0};
    f32x4 ac3 = {0,0,0,0}, ac4 = {0,0,0,0}, ac5 = {0,0,0,0};
    float xn0 = 0.f, xn1 = 0.f;
    if (lane < 16) {
      ac0[0] = xr[lane] + bh0;      ac1[0] = xr[16 + lane] + bh1;
      ac2[0] = xr[32 + lane] + bh2; ac3[0] = xr[48 + lane] + bh3;
      ac4[0] = bh4;                 ac5[0] = bh5;
      xn0 = xr[64 + lane];          xn1 = xr[80 + lane];
    }
    ac0 = MFMA(a, G0, ac0, 0, 0, 0); ac1 = MFMA(a, G1, ac1, 0, 0, 0);
    ac2 = MFMA(a, G2, ac2, 0, 0, 0); ac3 = MFMA(a, G3, ac3, 0, 0, 0);
    ac4 = MFMA(a, G4, ac4, 0, 0, 0); ac5 = MFMA(a, G5, ac5, 0, 0, 0);
    if (lane < 16) {
      float r0 = fsig(ac0[0]), r1 = fsig(ac1[0]);
      float z0 = fsig(ac2[0]), z1 = fsig(ac3[0]);
      float n0 = ftanh(xn0 + r0 * ac4[0]);
      float n1 = ftanh(xn1 + r1 * ac5[0]);
      h0 = (1.f - z0) * n0 + z0 * h0;
      h1 = (1.f - z1) * n1 + z1 * h1;
      mx0 = fmaxf(mx0, h0); mx1 = fmaxf(mx1, h1);
      hls[w][lane]      = (short)f2bf(h0);
      hls[w][16 + lane] = (short)f2bf(h1);
    }
  }
  if (lane < 16) {
    code[(size_t)seq * 64 + dir * 32 + lane]      = mx0;
    code[(size_t)seq * 64 + dir * 32 + 16 + lane] = mx1;
  }
}

// ---------------------------------------------------------------------------
// LSTM v14 (MFMA, wave-local gates, 1 barrier/step, 2+2 split MFMA chains:
// only acc[0] is consumed so the chain pairs sum with one scalar add each,
// halving the dependent-MFMA depth).
// ---------------------------------------------------------------------------
__global__ __launch_bounds__(512) void k_lstm(
    const float* __restrict__ xeL, const u32* __restrict__ Wpk,
    const float* __restrict__ bh, float* __restrict__ lout) {
  __shared__ float xl[SEQ * 512];
  __shared__ float hh[SEQ * 128];
  __shared__ s16x8 hl8[16];
  short* hls = (short*)hl8;
  int b = blockIdx.x, t = threadIdx.x;
  int w = t >> 6, lane = t & 63;
  const float* xrow = xeL + (size_t)b * SEQ * 512;
  #pragma unroll 5
  for (int i = t; i < SEQ * 512; i += 512) xl[i] = xrow[i];
  const s16x8* WB = (const s16x8*)Wpk + (size_t)w * 16 * 64 + lane;
  s16x8 B00 = WB[0*64],  B01 = WB[1*64],  B02 = WB[2*64],  B03 = WB[3*64];
  s16x8 B10 = WB[4*64],  B11 = WB[5*64],  B12 = WB[6*64],  B13 = WB[7*64];
  s16x8 B20 = WB[8*64],  B21 = WB[9*64],  B22 = WB[10*64], B23 = WB[11*64];
  s16x8 B30 = WB[12*64], B31 = WB[13*64], B32 = WB[14*64], B33 = WB[15*64];

  int u16 = 16 * w + lane;
  float bh0 = 0, bh1 = 0, bh2 = 0, bh3 = 0;
  if (lane < 16) {
    bh0 = bh[u16]; bh1 = bh[128 + u16]; bh2 = bh[256 + u16]; bh3 = bh[384 + u16];
  }
  float c = 0.f;
  if (t < 128) hls[t] = 0;
  __syncthreads();
  const s16x8 zz = {0, 0, 0, 0, 0, 0, 0, 0};
  const f32x4 zf = {0.f, 0.f, 0.f, 0.f};
  const bool arow = (lane & 15) == 0;
  const int asel = lane >> 4;
  for (int step = 0; step < SEQ; step++) {
    s16x8 a0 = arow ? hl8[asel]      : zz;
    s16x8 a1 = arow ? hl8[4 + asel]  : zz;
    s16x8 a2 = arow ? hl8[8 + asel]  : zz;
    s16x8 a3 = arow ? hl8[12 + asel] : zz;
    f32x4 acc0 = zf, acc1 = zf, acc2 = zf, acc3 = zf;
    f32x4 t0 = zf, t1 = zf, t2 = zf, t3 = zf;
    if (lane < 16) {
      const float* xs = xl + step * 512;
      acc0[0] = xs[u16]       + bh0;   // i
      acc1[0] = xs[128 + u16] + bh1;   // f
      acc2[0] = xs[256 + u16] + bh2;   // g
      acc3[0] = xs[384 + u16] + bh3;   // o
    }
    acc0 = MFMA(a0, B00, acc0, 0, 0, 0); acc0 = MFMA(a1, B01, acc0, 0, 0, 0);
    t0   = MFMA(a2, B02, t0,   0, 0, 0); t0   = MFMA(a3, B03, t0,   0, 0, 0);
    acc1 = MFMA(a0, B10, acc1, 0, 0, 0); acc1 = MFMA(a1, B11, acc1, 0, 0, 0);
    t1   = MFMA(a2, B12, t1,   0, 0, 0); t1   = MFMA(a3, B13, t1,   0, 0, 0);
    acc2 = MFMA(a0, B20, acc2, 0, 0, 0); acc2 = MFMA(a1, B21, acc2, 0, 0, 0);
    t2   = MFMA(a2, B22, t2,   0, 0, 0); t2   = MFMA(a3, B23, t2,   0, 0, 0);
    acc3 = MFMA(a0, B30, acc3, 0, 0, 0); acc3 = MFMA(a1, B31, acc3, 0, 0, 0);
    t3   = MFMA(a2, B32, t3,   0, 0, 0); t3   = MFMA(a3, B33, t3,   0, 0, 0);
    if (lane < 16) {
      float iv = fsig(acc0[0] + t0[0]);
      float fv = fsig(acc1[0] + t1[0]);
      float gv = ftanh(acc2[0] + t2[0]);
      float ov = fsig(acc3[0] + t3[0]);
      c = fv * c + iv * gv;
      float h = ov * ftanh(c);
      hh[step * 128 + u16] = h;
      hls[u16] = (short)f2bf(h);
    }
    __syncthreads();
  }
  float* lo = lout + (size_t)b * SEQ * 128;
  #pragma unroll 4
  for (int i = t; i < SEQ * 128; i += 512) lo[i] = hh[i];
}

// ---------------------------------------------------------------------------
// Prediction head with one-hot fast path (generic fallback preserved).
// ---------------------------------------------------------------------------
__global__ __launch_bounds__(128) void k_pred(const float* __restrict__ lout,
    const float* __restrict__ pred_w, const float* __restrict__ pred_b,
    const float* __restrict__ tc, const float* __restrict__ result,
    float* __restrict__ out, float* __restrict__ fpbuf, float* __restrict__ mbuf) {
  int row = blockIdx.x; int k = threadIdx.x;
  __shared__ float tcs[101];
  __shared__ float r1[128], r2[128], r3[128];
  if (k < 101) tcs[k] = tc[(size_t)row * 101 + k];
  __syncthreads();
  float nz = 0.f, ixs = 0.f, vs = 0.f;
  if (k < 101 && tcs[k] != 0.f) { nz = 1.f; ixs = (float)k; vs = tcs[k]; }
  r1[k] = nz; r2[k] = ixs; r3[k] = vs;
  __syncthreads();
  for (int st = 64; st > 0; st >>= 1) {
    if (k < st) { r1[k] += r1[k + st]; r2[k] += r2[k + st]; r3[k] += r3[k + st]; }
    __syncthreads();
  }
  float cnt = r1[0], idxf = r2[0], ncon = r3[0];
  __syncthreads();
  float fp, m;
  if (cnt == 1.f && ncon == 1.f) {
    int cls = (int)idxf;
    float v = lout[(size_t)row * 128 + k] * pred_w[cls * 128 + k];
    r1[k] = v;
    __syncthreads();
    for (int st = 64; st > 0; st >>= 1) {
      if (k < st) r1[k] += r1[k + st];
      __syncthreads();
    }
    fp = r1[0] + pred_b[cls];
    m = 1.f;
  } else {
    float lk = lout[(size_t)row * 128 + k];
    float acc = 0.f;
    for (int c = 0; c < 101; c++) acc += tcs[c] * pred_w[c * 128 + k];
    float v = acc * lk;
    float pb = (k < 101) ? tcs[k] * pred_b[k] : 0.f;
    r1[k] = v; r2[k] = pb;
    __syncthreads();
    for (int st = 64; st > 0; st >>= 1) {
      if (k < st) { r1[k] += r1[k + st]; r2[k] += r2[k + st]; }
      __syncthreads();
    }
    m = (ncon > 0.f) ? 1.f : 0.f;
    fp = (r1[0] + r2[0]) / fmaxf(ncon, 1.f);
  }
  if (k == 0) {
    fpbuf[row] = fp; mbuf[row] = m;
    out[1 + row] = m / (1.f + expf(-fp));
    out[1 + NROW + row] = result[row] * m;
  }
}

// ---------------------------------------------------------------------------
// Loss reduction (single block, deterministic tree reduce)
// ---------------------------------------------------------------------------
__global__ __launch_bounds__(256) void k_loss(const float* __restrict__ fpbuf,
    const float* __restrict__ mbuf, const float* __restrict__ result,
    float* __restrict__ out) {
  __shared__ float sb[256], sm[256];
  int k = threadIdx.x;
  float ab = 0.f, am = 0.f;
  for (int r = k; r < NROW; r += 256) {
    float fp = fpbuf[r], m = mbuf[r], res = result[r];
    float bce = fmaxf(fp, 0.f) - fp * res + log1pf(expf(-fabsf(fp)));
    ab += bce * m; am += m;
  }
  sb[k] = ab; sm[k] = am;
  __syncthreads();
  for (int st = 128; st > 0; st >>= 1) {
    if (k < st) { sb[k] += sb[k + st]; sm[k] += sm[k + st]; }
    __syncthreads();
  }
  if (k == 0) out[0] = sb[0] / fmaxf(sm[0], 1.f);
}

// ---------------------------------------------------------------------------
extern "C" void kernel_launch(void* const* d_in, const int* in_sizes, int n_in,
                              void* d_out, int out_size, void* d_ws, size_t ws_size,
                              hipStream_t stream) {
  (void)in_sizes; (void)n_in; (void)out_size; (void)ws_size;
  const int*   ast      = (const int*)  d_in[2];
  const float* target_c = (const float*)d_in[3];
  const float* c_embed  = (const float*)d_in[4];
  const float* cur_res  = (const float*)d_in[5];
  const float* result   = (const float*)d_in[6];
  const float* emb      = (const float*)d_in[7];
  const float* Wc_w     = (const float*)d_in[8];
  const float* Wc_b     = (const float*)d_in[9];
  const float* gru_WxF  = (const float*)d_in[10];
  const float* gru_WhF  = (const float*)d_in[11];
  const float* gru_bxF  = (const float*)d_in[12];
  const float* gru_bhF  = (const float*)d_in[13];
  const float* gru_WxB  = (const float*)d_in[14];
  const float* gru_WhB  = (const float*)d_in[15];
  const float* gru_bxB  = (const float*)d_in[16];
  const float* gru_bhB  = (const float*)d_in[17];
  const float* lstm_Wx  = (const float*)d_in[18];
  const float* lstm_Wh  = (const float*)d_in[19];
  const float* lstm_bx  = (const float*)d_in[20];
  const float* lstm_bh  = (const float*)d_in[21];
  const float* pred_w   = (const float*)d_in[22];
  const float* pred_b   = (const float*)d_in[23];
  float* out = (float*)d_out;

  float* W = (float*)d_ws;
  u32*   Epb    = (u32*)W;                       // 3,200,000 (50000x128 bf16)
  float* xe_all = W + 3200000;                   // 4,915,200
  float* code   = W + 8115200;                   // 102,400
  float* xeL    = W + 8217600;                   // 819,200
  float* lout   = W + 9036800;                   // 204,800
  float* fpbuf  = W + 9241600;                   // 1,600
  float* mbuf   = W + 9243200;                   // 1,600
  u32*   Wallpk = (u32*)(W + 9244800);           // 12,288
  u32*   Wxpk   = (u32*)(W + 9257088);           // 49,152
  u32*   Wpk    = (u32*)(W + 9306240);           // 32,768
  float* ball   = W + 9339008;                   // 192
  u32*   Wgpk   = (u32*)(W + 9339200);           // 3,072

  // 1. MERGED: Ep = emb @ Wc_w^T (inline B-pack, bf16 out) + weight prep
  k_ep_prep<<<974, 256, 0, stream>>>(emb, Wc_w, gru_WxF, gru_WxB, gru_bxF,
                                     gru_bxB, lstm_Wx, lstm_Wh, gru_WhF,
                                     gru_WhB, (unsigned short*)Epb, ball,
                                     Wallpk, Wxpk, Wpk, Wgpk);
  // 2. FUSED tree gather/sum/max + xe_all GEMM (MFMA, fp32 out, N=192)
  k_tree_xe<<<400, 256, 0, stream>>>(ast, Epb, Wc_b, Wallpk, ball, xe_all);
  // 3. GRU recurrence + time max -> code (MFMA, wave per (seq,dir))
  k_gru<<<NROW / 2, 256, 0, stream>>>(xe_all, Wgpk, gru_bhF, gru_bhB, code);
  // 4. xeL = [c_embed|code|cur|0] @ lstm_Wx^T + lstm_bx (fused lin, K=192 MFMA)
  gemm_lin<<<25, 256, 0, stream>>>(c_embed, code, cur_res, Wxpk, lstm_bx, xeL);
  // 5. LSTM recurrence -> lout (MFMA, wave-local gates, split chains)
  k_lstm<<<BS, 512, 0, stream>>>(xeL, Wpk, lstm_bh, lout);
  // 6. prediction head (one-hot fast path) -> out[1..], fpbuf, mbuf
  k_pred<<<NROW, 128, 0, stream>>>(lout, pred_w, pred_b, target_c, result,
                                   out, fpbuf, mbuf);
  // 7. loss -> out[0]
  k_loss<<<1, 256, 0, stream>>>(fpbuf, mbuf, result, out);
}

// Round 21
// 133.077 us; speedup vs baseline: 1.3457x; 1.1531x over previous
//
#include <hip/hip_runtime.h>
#include <hip/hip_bf16.h>
#include <math.h>

// Problem constants
#define BS 32
#define SEQ 50
#define ML 16
#define NN 15
#define NTREE (BS*SEQ*ML)     // 25600
#define NROW (BS*SEQ)         // 1600
#define VOCAB 50000
#define EMB 128
#define ENC 128
#define GH 32
#define NC 100
#define LH 128
#define LIN_D 167             // 101 + 64 + 2

typedef float f32x4 __attribute__((ext_vector_type(4)));
typedef short s16x8 __attribute__((ext_vector_type(8)));
typedef unsigned int u32;
typedef u32 u32x4v __attribute__((ext_vector_type(4)));

#define LOG2E 1.4426950408889634f
__device__ __forceinline__ float fsig(float x) {
  return __builtin_amdgcn_rcpf(1.f + __builtin_amdgcn_exp2f(-LOG2E * x));
}
__device__ __forceinline__ float ftanh(float x) {
  return 2.f * __builtin_amdgcn_rcpf(
             1.f + __builtin_amdgcn_exp2f(-2.f * LOG2E * x)) - 1.f;
}
__device__ __forceinline__ u32 pkbf(float x, float y) {
  u32 a = __float_as_uint(x), b = __float_as_uint(y);
  a = (a + 0x7FFFu + ((a >> 16) & 1u)) >> 16;
  b = (b + 0x7FFFu + ((b >> 16) & 1u)) >> 16;
  return a | (b << 16);
}
__device__ __forceinline__ unsigned short f2bf(float x) {
  u32 a = __float_as_uint(x);
  return (unsigned short)((a + 0x7FFFu + ((a >> 16) & 1u)) >> 16);
}
#define MFMA __builtin_amdgcn_mfma_f32_16x16x32_bf16

// ---------------------------------------------------------------------------
// MFMA GEMM (K=128, A fp32 packed on the fly): used for Ep (bf16 out).
// ---------------------------------------------------------------------------
__global__ __launch_bounds__(256) void gemm_mfma(
    const float* __restrict__ A, const u32* __restrict__ Bpk,
    const float* __restrict__ bias, void* __restrict__ Cout,
    int M, int N, int out_bf16) {
  int w = threadIdx.x >> 6, lane = threadIdx.x & 63;
  int R0 = blockIdx.x * 64 + w * 16;
  int r = R0 + (lane & 15);
  int rm = (r < M) ? r : (M - 1);
  const float* Ar = A + (size_t)rm * 128 + (lane >> 4) * 8;
  s16x8 a0, a1, a2, a3;
  {
#define LDA(AF, KT) { \
    float4 f0 = *(const float4*)(Ar + KT * 32); \
    float4 f1 = *(const float4*)(Ar + KT * 32 + 4); \
    u32x4v q = {pkbf(f0.x, f0.y), pkbf(f0.z, f0.w), \
                pkbf(f1.x, f1.y), pkbf(f1.z, f1.w)}; \
    AF = __builtin_bit_cast(s16x8, q); }
    LDA(a0, 0) LDA(a1, 1) LDA(a2, 2) LDA(a3, 3)
#undef LDA
  }
  const u32x4v* Bp = (const u32x4v*)Bpk;
  for (int c = 0; c < N; c += 64) {
    f32x4 acc0, acc1, acc2, acc3;
    {
      float b0 = bias ? bias[c + (lane & 15)]      : 0.f;
      float b1 = bias ? bias[c + 16 + (lane & 15)] : 0.f;
      float b2 = bias ? bias[c + 32 + (lane & 15)] : 0.f;
      float b3 = bias ? bias[c + 48 + (lane & 15)] : 0.f;
      acc0 = (f32x4){b0, b0, b0, b0}; acc1 = (f32x4){b1, b1, b1, b1};
      acc2 = (f32x4){b2, b2, b2, b2}; acc3 = (f32x4){b3, b3, b3, b3};
    }
    int fbase = (c >> 4) * 4;
#define DONT(ACC, NT) { \
    s16x8 bf0 = __builtin_bit_cast(s16x8, Bp[(size_t)(fbase + NT * 4 + 0) * 64 + lane]); \
    s16x8 bf1 = __builtin_bit_cast(s16x8, Bp[(size_t)(fbase + NT * 4 + 1) * 64 + lane]); \
    s16x8 bf2 = __builtin_bit_cast(s16x8, Bp[(size_t)(fbase + NT * 4 + 2) * 64 + lane]); \
    s16x8 bf3 = __builtin_bit_cast(s16x8, Bp[(size_t)(fbase + NT * 4 + 3) * 64 + lane]); \
    ACC = MFMA(a0, bf0, ACC, 0, 0, 0); ACC = MFMA(a1, bf1, ACC, 0, 0, 0); \
    ACC = MFMA(a2, bf2, ACC, 0, 0, 0); ACC = MFMA(a3, bf3, ACC, 0, 0, 0); }
    DONT(acc0, 0) DONT(acc1, 1) DONT(acc2, 2) DONT(acc3, 3)
#undef DONT
    int colb = c + (lane & 15);
    int rowb = R0 + (lane >> 4) * 4;
#define STNT(ACC, NT) \
    _Pragma("unroll") \
    for (int j = 0; j < 4; j++) { \
      int row = rowb + j; \
      if (row < M) { \
        if (out_bf16) ((unsigned short*)Cout)[(size_t)row * N + colb + NT * 16] = f2bf(ACC[j]); \
        else ((float*)Cout)[(size_t)row * N + colb + NT * 16] = ACC[j]; \
      } \
    }
    STNT(acc0, 0) STNT(acc1, 1) STNT(acc2, 2) STNT(acc3, 3)
#undef STNT
  }
}

// ---------------------------------------------------------------------------
// MFMA GEMM (K=128, A bf16 direct): used for xe_all = x_bf @ Wall^T + ball.
// ---------------------------------------------------------------------------
__global__ __launch_bounds__(256) void gemm_mfma_bfA(
    const unsigned short* __restrict__ Ab, const u32* __restrict__ Bpk,
    const float* __restrict__ bias, float* __restrict__ Cout,
    int M, int N) {
  int w = threadIdx.x >> 6, lane = threadIdx.x & 63;
  int R0 = blockIdx.x * 64 + w * 16;
  int r = R0 + (lane & 15);
  int rm = (r < M) ? r : (M - 1);
  const unsigned short* Ar = Ab + (size_t)rm * 128 + (lane >> 4) * 8;
  s16x8 a0 = *(const s16x8*)(Ar + 0);
  s16x8 a1 = *(const s16x8*)(Ar + 32);
  s16x8 a2 = *(const s16x8*)(Ar + 64);
  s16x8 a3 = *(const s16x8*)(Ar + 96);
  const u32x4v* Bp = (const u32x4v*)Bpk;
  for (int c = 0; c < N; c += 64) {
    f32x4 acc0, acc1, acc2, acc3;
    {
      float b0 = bias[c + (lane & 15)];
      float b1 = bias[c + 16 + (lane & 15)];
      float b2 = bias[c + 32 + (lane & 15)];
      float b3 = bias[c + 48 + (lane & 15)];
      acc0 = (f32x4){b0, b0, b0, b0}; acc1 = (f32x4){b1, b1, b1, b1};
      acc2 = (f32x4){b2, b2, b2, b2}; acc3 = (f32x4){b3, b3, b3, b3};
    }
    int fbase = (c >> 4) * 4;
#define DONT(ACC, NT) { \
    s16x8 bf0 = __builtin_bit_cast(s16x8, Bp[(size_t)(fbase + NT * 4 + 0) * 64 + lane]); \
    s16x8 bf1 = __builtin_bit_cast(s16x8, Bp[(size_t)(fbase + NT * 4 + 1) * 64 + lane]); \
    s16x8 bf2 = __builtin_bit_cast(s16x8, Bp[(size_t)(fbase + NT * 4 + 2) * 64 + lane]); \
    s16x8 bf3 = __builtin_bit_cast(s16x8, Bp[(size_t)(fbase + NT * 4 + 3) * 64 + lane]); \
    ACC = MFMA(a0, bf0, ACC, 0, 0, 0); ACC = MFMA(a1, bf1, ACC, 0, 0, 0); \
    ACC = MFMA(a2, bf2, ACC, 0, 0, 0); ACC = MFMA(a3, bf3, ACC, 0, 0, 0); }
    DONT(acc0, 0) DONT(acc1, 1) DONT(acc2, 2) DONT(acc3, 3)
#undef DONT
    int colb = c + (lane & 15);
    int rowb = R0 + (lane >> 4) * 4;
#define STNT(ACC, NT) \
    _Pragma("unroll") \
    for (int j = 0; j < 4; j++) { \
      int row = rowb + j; \
      if (row < M) Cout[(size_t)row * N + colb + NT * 16] = ACC[j]; \
    }
    STNT(acc0, 0) STNT(acc1, 1) STNT(acc2, 2) STNT(acc3, 3)
#undef STNT
  }
}

// ---------------------------------------------------------------------------
// Fused lin-gather + MFMA GEMM (K=192, KT=6): xeL = [c_embed|code|cur|0] @
// Wxpk^T + lstm_bx. M=1600 (25 blocks), N=512, fp32 out.
// ---------------------------------------------------------------------------
__device__ __forceinline__ float lin_at(const float* __restrict__ ce,
    const float* __restrict__ co, const float* __restrict__ cu,
    int row, int k) {
  if (k < 101) return ce[row * 101 + k];
  if (k < 165) return co[row * 64 + (k - 101)];
  if (k < 167) return cu[row * 2 + (k - 165)];
  return 0.f;
}

__global__ __launch_bounds__(256) void gemm_lin(
    const float* __restrict__ c_embed, const float* __restrict__ code,
    const float* __restrict__ cur, const u32* __restrict__ Bpk,
    const float* __restrict__ bias, float* __restrict__ Cout) {
  int w = threadIdx.x >> 6, lane = threadIdx.x & 63;
  int R0 = blockIdx.x * 64 + w * 16;
  int r = R0 + (lane & 15);
  s16x8 a[6];
  #pragma unroll
  for (int kt = 0; kt < 6; kt++) {
    int k0 = kt * 32 + (lane >> 4) * 8;
    float f[8];
    #pragma unroll
    for (int j = 0; j < 8; j++) f[j] = lin_at(c_embed, code, cur, r, k0 + j);
    u32x4v q = {pkbf(f[0], f[1]), pkbf(f[2], f[3]),
                pkbf(f[4], f[5]), pkbf(f[6], f[7])};
    a[kt] = __builtin_bit_cast(s16x8, q);
  }
  const u32x4v* Bp = (const u32x4v*)Bpk;
  for (int c = 0; c < 512; c += 64) {
    f32x4 acc[4];
    #pragma unroll
    for (int nt = 0; nt < 4; nt++) {
      float bv = bias[c + nt * 16 + (lane & 15)];
      acc[nt] = (f32x4){bv, bv, bv, bv};
    }
    int fbase = (c >> 4) * 6;
    #pragma unroll
    for (int nt = 0; nt < 4; nt++) {
      #pragma unroll
      for (int kt = 0; kt < 6; kt++) {
        s16x8 bf = __builtin_bit_cast(s16x8,
            Bp[(size_t)(fbase + nt * 6 + kt) * 64 + lane]);
        acc[nt] = MFMA(a[kt], bf, acc[nt], 0, 0, 0);
      }
    }
    int colb = c + (lane & 15);
    int rowb = R0 + (lane >> 4) * 4;
    #pragma unroll
    for (int nt = 0; nt < 4; nt++)
      #pragma unroll
      for (int j = 0; j < 4; j++)
        Cout[(size_t)(rowb + j) * 512 + colb + nt * 16] = acc[nt][j];
  }
}

// ---------------------------------------------------------------------------
// Prep: ball; MFMA B-frag packs: Wcpk (N=128,KT=4), Wallpk (N=192,KT=4),
// Wxpk (N=512,KT=6), Wpk (lstm, wave-local gates), Wgpk (GRU Wh, K=32).
// ---------------------------------------------------------------------------
__global__ __launch_bounds__(256) void k_prep(const float* __restrict__ WxF,
    const float* __restrict__ WxB, const float* __restrict__ bxF,
    const float* __restrict__ bxB, const float* __restrict__ lstm_Wx,
    const float* __restrict__ lstm_Wh, const float* __restrict__ Wc_w,
    const float* __restrict__ gru_WhF, const float* __restrict__ gru_WhB,
    float* __restrict__ ball, u32* __restrict__ Wcpk,
    u32* __restrict__ Wallpk, u32* __restrict__ Wxpk, u32* __restrict__ Wpk,
    u32* __restrict__ Wgpk) {
  int i = blockIdx.x * 256 + threadIdx.x;
  if (i < 96) ball[i] = bxF[i];
  else if (i < 192) ball[i] = bxB[i - 96];
  if (i < 8192) {   // Wcpk
    int fg = i >> 8, l = (i >> 2) & 63, p = i & 3;
    int nt = fg >> 2, kt = fg & 3;
    int n = nt * 16 + (l & 15);
    int k = kt * 32 + (l >> 4) * 8 + 2 * p;
    Wcpk[i] = pkbf(Wc_w[n * 128 + k], Wc_w[n * 128 + k + 1]);
  }
  if (i < 12288) {  // Wallpk (N=192)
    int fg = i >> 8, l = (i >> 2) & 63, p = i & 3;
    int nt = fg >> 2, kt = fg & 3;
    int n = nt * 16 + (l & 15);
    int k = kt * 32 + (l >> 4) * 8 + 2 * p;
    float v0 = (n < 96) ? WxF[n * 128 + k]     : WxB[(n - 96) * 128 + k];
    float v1 = (n < 96) ? WxF[n * 128 + k + 1] : WxB[(n - 96) * 128 + k + 1];
    Wallpk[i] = pkbf(v0, v1);
  }
  if (i < 49152) {  // Wxpk (N=512, KT=6, K padded 167->192)
    int fg = i >> 8, l = (i >> 2) & 63, p = i & 3;
    int nt = fg / 6, kt = fg % 6;
    int n = nt * 16 + (l & 15);
    int k = kt * 32 + (l >> 4) * 8 + 2 * p;
    float v0 = (k < LIN_D)     ? lstm_Wx[n * LIN_D + k]     : 0.f;
    float v1 = (k + 1 < LIN_D) ? lstm_Wx[n * LIN_D + k + 1] : 0.f;
    Wxpk[i] = pkbf(v0, v1);
  }
  if (i < 32768) {  // Wpk: wave-local gates. fg = w*16 + gt*4 + kt
    int fg = i >> 8, l = (i >> 2) & 63, p = i & 3;
    int w = fg >> 4, gt = (fg >> 2) & 3, kt = fg & 3;
    int n = 128 * gt + 16 * w + (l & 15);
    int k = 32 * kt + 8 * (l >> 4) + 2 * p;
    Wpk[i] = pkbf(lstm_Wh[n * 128 + k], lstm_Wh[n * 128 + k + 1]);
  }
  if (i < 3072) {   // Wgpk: GRU Wh (96x32), fg = dir*6 + nt
    int fg = i >> 8, l = (i >> 2) & 63, p = i & 3;
    int dir = fg / 6, nt = fg % 6;
    int n = nt * 16 + (l & 15);
    int k = (l >> 4) * 8 + 2 * p;
    const float* Wh = dir ? gru_WhB : gru_WhF;
    Wgpk[i] = pkbf(Wh[n * 32 + k], Wh[n * 32 + k + 1]);
  }
}

// ---------------------------------------------------------------------------
// Tree: gather 15 bf16 rows of Ep, subtree sums, node max. bf16 out.
// ---------------------------------------------------------------------------
__global__ __launch_bounds__(256) void k_tree(const int* __restrict__ ast,
    const u32* __restrict__ Epb, const float* __restrict__ Wc_b,
    unsigned short* __restrict__ x_bf) {
  int lt = threadIdx.x >> 7;
  int d  = threadIdx.x & 127;
  int tree = blockIdx.x * 2 + lt;
  __shared__ int toks[2][15];
  if (d < 15) toks[lt][d] = ast[(size_t)tree * 15 + d];
  __syncthreads();
  float e[15];
  int half = d >> 1;
  bool odd = (d & 1) != 0;
  #pragma unroll
  for (int n = 0; n < 15; n++) {
    u32 v = Epb[(size_t)toks[lt][n] * 64 + half];
    e[n] = __uint_as_float(odd ? (v & 0xFFFF0000u) : (v << 16));
  }
  float b = Wc_b[d];
  float s3 = e[3] + e[7] + e[8],  s4 = e[4] + e[9] + e[10];
  float s5 = e[5] + e[11] + e[12], s6 = e[6] + e[13] + e[14];
  float s1 = e[1] + s3 + s4, s2 = e[2] + s5 + s6;
  float s0 = e[0] + s1 + s2;
  float ml = fmaxf(fmaxf(fmaxf(e[7], e[8]), fmaxf(e[9], e[10])),
                   fmaxf(fmaxf(e[11], e[12]), fmaxf(e[13], e[14]))) + b;
  float mm = fmaxf(fmaxf(s3, s4), fmaxf(s5, s6)) + 3.f * b;
  float mt = fmaxf(s1, s2) + 7.f * b;
  float m = fmaxf(fmaxf(ml, mm), fmaxf(mt, s0 + 15.f * b));
  x_bf[(size_t)tree * 128 + d] = f2bf(m);
}

// ---------------------------------------------------------------------------
// GRU v2 (MFMA, one wave per (seq,dir), NO barriers in the step loop).
// ---------------------------------------------------------------------------
__global__ __launch_bounds__(256) void k_gru(const float* __restrict__ xe_all,
    const u32* __restrict__ Wgpk, const float* __restrict__ bhF,
    const float* __restrict__ bhB, float* __restrict__ code) {
  __shared__ float xls[32 * 192];    // 24 KB: 2 sequences x 16 steps x 192
  __shared__ short hls[4][32];
  int t = threadIdx.x, w = t >> 6, lane = t & 63;
  int sq0 = blockIdx.x * 2;
  const float* xb = xe_all + (size_t)sq0 * 16 * 192;
  #pragma unroll 4
  for (int i = t; i < 32 * 192; i += 256) xls[i] = xb[i];
  int sql = w >> 1, dir = w & 1;
  int seq = sq0 + sql;
  const s16x8* BG = (const s16x8*)Wgpk + (size_t)dir * 6 * 64 + lane;
  s16x8 G0 = BG[0], G1 = BG[64], G2 = BG[128];
  s16x8 G3 = BG[192], G4 = BG[256], G5 = BG[320];
  const float* bh = dir ? bhB : bhF;
  float bh0 = 0, bh1 = 0, bh2 = 0, bh3 = 0, bh4 = 0, bh5 = 0;
  if (lane < 16) {
    bh0 = bh[lane];      bh1 = bh[16 + lane]; bh2 = bh[32 + lane];
    bh3 = bh[48 + lane]; bh4 = bh[64 + lane]; bh5 = bh[80 + lane];
  }
  float h0 = 0.f, h1 = 0.f, mx0 = -1e30f, mx1 = -1e30f;
  hls[w][lane & 31] = 0;
  __syncthreads();
  const s16x8 zz = {0, 0, 0, 0, 0, 0, 0, 0};
  const bool arow = (lane & 15) == 0;
  const int aoff = (lane >> 4) * 8;
  for (int s = 0; s < 16; s++) {
    int tt = dir ? (15 - s) : s;
    const float* xr = xls + (sql * 16 + tt) * 192 + dir * 96;
    s16x8 a = arow ? *(const s16x8*)&hls[w][aoff] : zz;
    f32x4 ac0 = {0,0,0,0}, ac1 = {0,0,0,0}, ac2 = {0,0,0,0};
    f32x4 ac3 = {0,0,0,0}, ac4 = {0,0,0,0}, ac5 = {0,0,0,0};
    float xn0 = 0.f, xn1 = 0.f;
    if (lane < 16) {
      ac0[0] = xr[lane] + bh0;      ac1[0] = xr[16 + lane] + bh1;
      ac2[0] = xr[32 + lane] + bh2; ac3[0] = xr[48 + lane] + bh3;
      ac4[0] = bh4;                 ac5[0] = bh5;
      xn0 = xr[64 + lane];          xn1 = xr[80 + lane];
    }
    ac0 = MFMA(a, G0, ac0, 0, 0, 0); ac1 = MFMA(a, G1, ac1, 0, 0, 0);
    ac2 = MFMA(a, G2, ac2, 0, 0, 0); ac3 = MFMA(a, G3, ac3, 0, 0, 0);
    ac4 = MFMA(a, G4, ac4, 0, 0, 0); ac5 = MFMA(a, G5, ac5, 0, 0, 0);
    if (lane < 16) {
      float r0 = fsig(ac0[0]), r1 = fsig(ac1[0]);
      float z0 = fsig(ac2[0]), z1 = fsig(ac3[0]);
      float n0 = ftanh(xn0 + r0 * ac4[0]);
      float n1 = ftanh(xn1 + r1 * ac5[0]);
      h0 = (1.f - z0) * n0 + z0 * h0;
      h1 = (1.f - z1) * n1 + z1 * h1;
      mx0 = fmaxf(mx0, h0); mx1 = fmaxf(mx1, h1);
      hls[w][lane]      = (short)f2bf(h0);
      hls[w][16 + lane] = (short)f2bf(h1);
    }
  }
  if (lane < 16) {
    code[(size_t)seq * 64 + dir * 32 + lane]      = mx0;
    code[(size_t)seq * 64 + dir * 32 + 16 + lane] = mx1;
  }
}

// ---------------------------------------------------------------------------
// LSTM v13 (MFMA, wave-local gates): wave w owns hidden units 16w..16w+15
// and computes ALL FOUR gate types for them. Register-only c/h update,
// one barrier per step.
// ---------------------------------------------------------------------------
__global__ __launch_bounds__(512) void k_lstm(
    const float* __restrict__ xeL, const u32* __restrict__ Wpk,
    const float* __restrict__ bh, float* __restrict__ lout) {
  __shared__ float xl[SEQ * 512];    // 100 KB staged xe
  __shared__ float hh[SEQ * 128];    // 25.6 KB h history
  __shared__ s16x8 hl8[16];          // 256 B shared h (bf16)
  short* hls = (short*)hl8;
  int b = blockIdx.x, t = threadIdx.x;
  int w = t >> 6, lane = t & 63;
  const float* xrow = xeL + (size_t)b * SEQ * 512;
  #pragma unroll 5
  for (int i = t; i < SEQ * 512; i += 512) xl[i] = xrow[i];
  const s16x8* WB = (const s16x8*)Wpk + (size_t)w * 16 * 64 + lane;
  s16x8 B00 = WB[0*64],  B01 = WB[1*64],  B02 = WB[2*64],  B03 = WB[3*64];
  s16x8 B10 = WB[4*64],  B11 = WB[5*64],  B12 = WB[6*64],  B13 = WB[7*64];
  s16x8 B20 = WB[8*64],  B21 = WB[9*64],  B22 = WB[10*64], B23 = WB[11*64];
  s16x8 B30 = WB[12*64], B31 = WB[13*64], B32 = WB[14*64], B33 = WB[15*64];

  int u16 = 16 * w + lane;           // (lane<16) this thread's hidden unit
  float bh0 = 0, bh1 = 0, bh2 = 0, bh3 = 0;
  if (lane < 16) {
    bh0 = bh[u16]; bh1 = bh[128 + u16]; bh2 = bh[256 + u16]; bh3 = bh[384 + u16];
  }
  float c = 0.f;
  if (t < 128) hls[t] = 0;
  __syncthreads();
  const s16x8 zz = {0, 0, 0, 0, 0, 0, 0, 0};
  const bool arow = (lane & 15) == 0;
  const int asel = lane >> 4;
  for (int step = 0; step < SEQ; step++) {
    s16x8 a0 = arow ? hl8[asel]      : zz;
    s16x8 a1 = arow ? hl8[4 + asel]  : zz;
    s16x8 a2 = arow ? hl8[8 + asel]  : zz;
    s16x8 a3 = arow ? hl8[12 + asel] : zz;
    f32x4 acc0 = {0, 0, 0, 0}, acc1 = {0, 0, 0, 0};
    f32x4 acc2 = {0, 0, 0, 0}, acc3 = {0, 0, 0, 0};
    if (lane < 16) {
      const float* xs = xl + step * 512;
      acc0[0] = xs[u16]       + bh0;   // i
      acc1[0] = xs[128 + u16] + bh1;   // f
      acc2[0] = xs[256 + u16] + bh2;   // g
      acc3[0] = xs[384 + u16] + bh3;   // o
    }
    acc0 = MFMA(a0, B00, acc0, 0, 0, 0); acc0 = MFMA(a1, B01, acc0, 0, 0, 0);
    acc0 = MFMA(a2, B02, acc0, 0, 0, 0); acc0 = MFMA(a3, B03, acc0, 0, 0, 0);
    acc1 = MFMA(a0, B10, acc1, 0, 0, 0); acc1 = MFMA(a1, B11, acc1, 0, 0, 0);
    acc1 = MFMA(a2, B12, acc1, 0, 0, 0); acc1 = MFMA(a3, B13, acc1, 0, 0, 0);
    acc2 = MFMA(a0, B20, acc2, 0, 0, 0); acc2 = MFMA(a1, B21, acc2, 0, 0, 0);
    acc2 = MFMA(a2, B22, acc2, 0, 0, 0); acc2 = MFMA(a3, B23, acc2, 0, 0, 0);
    acc3 = MFMA(a0, B30, acc3, 0, 0, 0); acc3 = MFMA(a1, B31, acc3, 0, 0, 0);
    acc3 = MFMA(a2, B32, acc3, 0, 0, 0); acc3 = MFMA(a3, B33, acc3, 0, 0, 0);
    if (lane < 16) {
      float iv = fsig(acc0[0]);
      float fv = fsig(acc1[0]);
      float gv = ftanh(acc2[0]);
      float ov = fsig(acc3[0]);
      c = fv * c + iv * gv;
      float h = ov * ftanh(c);
      hh[step * 128 + u16] = h;
      hls[u16] = (short)f2bf(h);
    }
    __syncthreads();
  }
  float* lo = lout + (size_t)b * SEQ * 128;
  #pragma unroll 4
  for (int i = t; i < SEQ * 128; i += 512) lo[i] = hh[i];
}

// ---------------------------------------------------------------------------
// Prediction head with one-hot fast path (generic fallback preserved).
// ---------------------------------------------------------------------------
__global__ __launch_bounds__(128) void k_pred(const float* __restrict__ lout,
    const float* __restrict__ pred_w, const float* __restrict__ pred_b,
    const float* __restrict__ tc, const float* __restrict__ result,
    float* __restrict__ out, float* __restrict__ fpbuf, float* __restrict__ mbuf) {
  int row = blockIdx.x; int k = threadIdx.x;
  __shared__ float tcs[101];
  __shared__ float r1[128], r2[128], r3[128];
  if (k < 101) tcs[k] = tc[(size_t)row * 101 + k];
  __syncthreads();
  float nz = 0.f, ixs = 0.f, vs = 0.f;
  if (k < 101 && tcs[k] != 0.f) { nz = 1.f; ixs = (float)k; vs = tcs[k]; }
  r1[k] = nz; r2[k] = ixs; r3[k] = vs;
  __syncthreads();
  for (int st = 64; st > 0; st >>= 1) {
    if (k < st) { r1[k] += r1[k + st]; r2[k] += r2[k + st]; r3[k] += r3[k + st]; }
    __syncthreads();
  }
  float cnt = r1[0], idxf = r2[0], ncon = r3[0];
  __syncthreads();
  float fp, m;
  if (cnt == 1.f && ncon == 1.f) {
    int cls = (int)idxf;
    float v = lout[(size_t)row * 128 + k] * pred_w[cls * 128 + k];
    r1[k] = v;
    __syncthreads();
    for (int st = 64; st > 0; st >>= 1) {
      if (k < st) r1[k] += r1[k + st];
      __syncthreads();
    }
    fp = r1[0] + pred_b[cls];
    m = 1.f;
  } else {
    float lk = lout[(size_t)row * 128 + k];
    float acc = 0.f;
    for (int c = 0; c < 101; c++) acc += tcs[c] * pred_w[c * 128 + k];
    float v = acc * lk;
    float pb = (k < 101) ? tcs[k] * pred_b[k] : 0.f;
    r1[k] = v; r2[k] = pb;
    __syncthreads();
    for (int st = 64; st > 0; st >>= 1) {
      if (k < st) { r1[k] += r1[k + st]; r2[k] += r2[k + st]; }
      __syncthreads();
    }
    m = (ncon > 0.f) ? 1.f : 0.f;
    fp = (r1[0] + r2[0]) / fmaxf(ncon, 1.f);
  }
  if (k == 0) {
    fpbuf[row] = fp; mbuf[row] = m;
    out[1 + row] = m / (1.f + expf(-fp));
    out[1 + NROW + row] = result[row] * m;
  }
}

// ---------------------------------------------------------------------------
// Loss reduction (single block, deterministic tree reduce)
// ---------------------------------------------------------------------------
__global__ __launch_bounds__(256) void k_loss(const float* __restrict__ fpbuf,
    const float* __restrict__ mbuf, const float* __restrict__ result,
    float* __restrict__ out) {
  __shared__ float sb[256], sm[256];
  int k = threadIdx.x;
  float ab = 0.f, am = 0.f;
  for (int r = k; r < NROW; r += 256) {
    float fp = fpbuf[r], m = mbuf[r], res = result[r];
    float bce = fmaxf(fp, 0.f) - fp * res + log1pf(expf(-fabsf(fp)));
    ab += bce * m; am += m;
  }
  sb[k] = ab; sm[k] = am;
  __syncthreads();
  for (int st = 128; st > 0; st >>= 1) {
    if (k < st) { sb[k] += sb[k + st]; sm[k] += sm[k + st]; }
    __syncthreads();
  }
  if (k == 0) out[0] = sb[0] / fmaxf(sm[0], 1.f);
}

// ---------------------------------------------------------------------------
extern "C" void kernel_launch(void* const* d_in, const int* in_sizes, int n_in,
                              void* d_out, int out_size, void* d_ws, size_t ws_size,
                              hipStream_t stream) {
  (void)in_sizes; (void)n_in; (void)out_size; (void)ws_size;
  const int*   ast      = (const int*)  d_in[2];
  const float* target_c = (const float*)d_in[3];
  const float* c_embed  = (const float*)d_in[4];
  const float* cur_res  = (const float*)d_in[5];
  const float* result   = (const float*)d_in[6];
  const float* emb      = (const float*)d_in[7];
  const float* Wc_w     = (const float*)d_in[8];
  const float* Wc_b     = (const float*)d_in[9];
  const float* gru_WxF  = (const float*)d_in[10];
  const float* gru_WhF  = (const float*)d_in[11];
  const float* gru_bxF  = (const float*)d_in[12];
  const float* gru_bhF  = (const float*)d_in[13];
  const float* gru_WxB  = (const float*)d_in[14];
  const float* gru_WhB  = (const float*)d_in[15];
  const float* gru_bxB  = (const float*)d_in[16];
  const float* gru_bhB  = (const float*)d_in[17];
  const float* lstm_Wx  = (const float*)d_in[18];
  const float* lstm_Wh  = (const float*)d_in[19];
  const float* lstm_bx  = (const float*)d_in[20];
  const float* lstm_bh  = (const float*)d_in[21];
  const float* pred_w   = (const float*)d_in[22];
  const float* pred_b   = (const float*)d_in[23];
  float* out = (float*)d_out;

  float* W = (float*)d_ws;
  u32*   Epb    = (u32*)W;                       // 3,200,000
  unsigned short* x_bf = (unsigned short*)(W + 3200000); // 1,638,400 f
  float* xe_all = W + 4838400;                   // 4,915,200
  float* code   = W + 9753600;                   // 102,400
  float* xeL    = W + 9856000;                   // 819,200
  float* lout   = W + 10675200;                  // 204,800
  float* fpbuf  = W + 10880000;                  // 1,600
  float* mbuf   = W + 10881600;                  // 1,600
  u32*   Wcpk   = (u32*)(W + 10883200);          // 8,192
  u32*   Wallpk = (u32*)(W + 10891392);          // 12,288
  u32*   Wxpk   = (u32*)(W + 10903680);          // 49,152
  u32*   Wpk    = (u32*)(W + 10952832);          // 32,768
  float* ball   = W + 10985600;                  // 192
  u32*   Wgpk   = (u32*)(W + 10985792);          // 3,072

  // 1. weight prep (frag packs)
  k_prep<<<192, 256, 0, stream>>>(gru_WxF, gru_WxB, gru_bxF, gru_bxB, lstm_Wx,
                                  lstm_Wh, Wc_w, gru_WhF, gru_WhB,
                                  ball, Wcpk, Wallpk, Wxpk, Wpk, Wgpk);
  // 2. Ep = emb @ Wc_w^T (MFMA, bf16 out)
  gemm_mfma<<<782, 256, 0, stream>>>(emb, Wcpk, nullptr, Epb, VOCAB, 128, 1);
  // 3. tree gather/sum/max -> x_bf (25600 x 128, bf16)
  k_tree<<<NTREE / 2, 256, 0, stream>>>(ast, Epb, Wc_b, x_bf);
  // 4. xe_all = x_bf @ Wall^T + ball (MFMA bf16-A, fp32 out, N=192)
  gemm_mfma_bfA<<<400, 256, 0, stream>>>(x_bf, Wallpk, ball, xe_all, NTREE, 192);
  // 5. GRU recurrence + time max -> code (MFMA, wave per (seq,dir), no barriers)
  k_gru<<<NROW / 2, 256, 0, stream>>>(xe_all, Wgpk, gru_bhF, gru_bhB, code);
  // 6. xeL = [c_embed|code|cur|0] @ lstm_Wx^T + lstm_bx (fused lin, K=192 MFMA)
  gemm_lin<<<25, 256, 0, stream>>>(c_embed, code, cur_res, Wxpk, lstm_bx, xeL);
  // 7. LSTM recurrence -> lout (MFMA, wave-local gates, 1 barrier/step)
  k_lstm<<<BS, 512, 0, stream>>>(xeL, Wpk, lstm_bh, lout);
  // 8. prediction head (one-hot fast path) -> out[1..], fpbuf, mbuf
  k_pred<<<NROW, 128, 0, stream>>>(lout, pred_w, pred_b, target_c, result,
                                   out, fpbuf, mbuf);
  // 9. loss -> out[0]
  k_loss<<<1, 256, 0, stream>>>(fpbuf, mbuf, result, out);
}